// Round 7
// baseline (79.210 us; speedup 1.0000x reference)
//
#include <hip/hip_runtime.h>
#include <hip/hip_bf16.h>
#include <math.h>

// Problem constants
constexpr int Nimg = 4;
constexpr int Cin  = 256;
constexpr int Hc   = 64;
constexpr int Wc   = 64;
constexpr int HWc  = Hc * Wc;          // 4096
constexpr int Mrows = Nimg * HWc;      // 16384
constexpr int Gg   = 16;
constexpr int K2c  = 9;
constexpr int OMC  = Gg * K2c * 3;     // 432
constexpr int C2c  = 256;
constexpr float EPSc = 1e-5f;

typedef __attribute__((ext_vector_type(8))) short short8v;   // 8 bf16 bits
typedef __attribute__((ext_vector_type(4))) float f32x4;

__device__ __forceinline__ unsigned short f2bf(float f) {
    return __builtin_bit_cast(unsigned short, __float2bfloat16(f));
}
__device__ __forceinline__ float bf2f(unsigned short u) {
    return __builtin_bit_cast(float, (unsigned)u << 16);
}

__device__ __forceinline__ void gload16(const unsigned short* g, unsigned short* l) {
    __builtin_amdgcn_global_load_lds(
        (const __attribute__((address_space(1))) void*)g,
        (__attribute__((address_space(3))) void*)l, 16, 0, 0);
}

// Accumulate 4 bf16 channels (8B at p) with weight wk into acc.
__device__ __forceinline__ void acc4(const unsigned short* p, float wk, float4& a) {
    const uint2 u = *reinterpret_cast<const uint2*>(p);
    a.x += wk * __builtin_bit_cast(float, u.x << 16);
    a.y += wk * __builtin_bit_cast(float, u.x & 0xffff0000u);
    a.z += wk * __builtin_bit_cast(float, u.y << 16);
    a.w += wk * __builtin_bit_cast(float, u.y & 0xffff0000u);
}

// ---------------------------------------------------------------------------
// Fused prep: blocks [0,1024) transpose+convert x (NCHW fp32 -> A[m][k] bf16);
// blocks [1024,2051) convert weights to transposed bf16 + concat bias.
// ---------------------------------------------------------------------------
__global__ __launch_bounds__(256) void prep(
    const float* __restrict__ x,
    const float* __restrict__ Wv, const float* __restrict__ Wom,
    const float* __restrict__ Wout,
    const float* __restrict__ bv, const float* __restrict__ bom,
    unsigned short* __restrict__ A,
    unsigned short* __restrict__ WallT, unsigned short* __restrict__ WoutT,
    float* __restrict__ ball)
{
    __shared__ float tile[64][65];
    const int t   = threadIdx.x;
    const int bid = blockIdx.x;
    if (bid < 1024) {
        const int p0 = (bid & 63) * 64;
        const int c0 = ((bid >> 6) & 3) * 64;
        const int n  = bid >> 8;
        const float* xb = x + ((size_t)n * Cin + c0) * HWc + p0;
#pragma unroll
        for (int i = 0; i < 16; i++) {
            const int c = i * 4 + (t >> 6);
            tile[c][t & 63] = xb[(size_t)c * HWc + (t & 63)];
        }
        __syncthreads();
        unsigned short* Ab = A + ((size_t)(n * HWc) + p0) * Cin + c0;
#pragma unroll
        for (int i = 0; i < 8; i++) {
            const int p  = i * 8 + (t >> 5);
            const int c2 = (t & 31) * 2;
            const unsigned lo = f2bf(tile[c2][p]);
            const unsigned hi = f2bf(tile[c2 + 1][p]);
            *(unsigned*)(Ab + (size_t)p * Cin + c2) = lo | (hi << 16);
        }
        return;
    }
    const int e = (bid - 1024) * 256 + t;
    if (e < 65536) {                       // Wv -> WallT rows 0..255
        const int nc = e >> 8, k = e & 255;
        WallT[e] = f2bf(Wv[(size_t)k * 256 + nc]);
    } else if (e < 196608) {               // Wom -> WallT rows 256..767 (pad)
        const int e2 = e - 65536;
        const int nc = e2 >> 8, k = e2 & 255;
        WallT[e] = f2bf(nc < 432 ? Wom[(size_t)k * 432 + nc] : 0.f);
    } else if (e < 262144) {               // Wout -> WoutT
        const int e3 = e - 196608;
        const int nc = e3 >> 8, k = e3 & 255;
        WoutT[e3] = f2bf(Wout[(size_t)k * 256 + nc]);
    } else if (e < 262912) {               // concat bias
        const int i = e - 262144;
        ball[i] = (i < 256) ? bv[i] : ((i < 688) ? bom[i - 256] : 0.f);
    }
}

// ---------------------------------------------------------------------------
// Fused v+om GEMM: [16384 x 768] = A[16384 x 256] @ WallT[768 x 256]^T + ball.
// 128x256 tile, BK=32, 8 waves (2x4). XCD-swizzled.
// ---------------------------------------------------------------------------
__global__ __launch_bounds__(512) void gemm_vom(
    const unsigned short* __restrict__ A,
    const unsigned short* __restrict__ Bt,
    const float* __restrict__ ball,
    unsigned short* __restrict__ vbf,
    unsigned short* __restrict__ ombf)
{
    __shared__ unsigned short As[128 * 32];
    __shared__ unsigned short Bs[256 * 32];
    const int t    = threadIdx.x;
    const int lane = t & 63;
    const int wid  = t >> 6;
    const int wr   = wid >> 2;
    const int wc   = wid & 3;
    const int vid = blockIdx.x + 3 * blockIdx.y;
    const int xcd = vid & 7;
    const int j8  = vid >> 3;             // 0..47
    const int row0 = (xcd * 16 + j8 / 3) * 128;
    const int col0 = (j8 % 3) * 256;

    f32x4 acc[4][4];
#pragma unroll
    for (int m = 0; m < 4; m++)
#pragma unroll
        for (int n = 0; n < 4; n++) acc[m][n] = (f32x4)0.f;

    const int r0   = t >> 2;
    const int koff = (t & 3) * 8;
    const unsigned short* gA  = A  + (size_t)(row0 + r0) * 256 + koff;
    const unsigned short* gB0 = Bt + (size_t)(col0 + r0) * 256 + koff;
    const unsigned short* gB1 = Bt + (size_t)(col0 + 128 + r0) * 256 + koff;
    const int sbase = wid * 512;

    const int arow = wr * 64 + (lane & 15);
    const int bcol = wc * 64 + (lane & 15);
    const int kq   = (lane >> 4) * 8;

    for (int k0 = 0; k0 < 256; k0 += 32) {
        gload16(gA  + k0, As + sbase);
        gload16(gB0 + k0, Bs + sbase);
        gload16(gB1 + k0, Bs + 4096 + sbase);
        __syncthreads();

        short8v a_[4], b_[4];
#pragma unroll
        for (int m = 0; m < 4; m++)
            a_[m] = *(const short8v*)(As + (arow + m * 16) * 32 + kq);
#pragma unroll
        for (int n = 0; n < 4; n++)
            b_[n] = *(const short8v*)(Bs + (bcol + n * 16) * 32 + kq);
#pragma unroll
        for (int m = 0; m < 4; m++)
#pragma unroll
            for (int n = 0; n < 4; n++)
                acc[m][n] = __builtin_amdgcn_mfma_f32_16x16x32_bf16(
                    a_[m], b_[n], acc[m][n], 0, 0, 0);
        __syncthreads();
    }

    const int rb = row0 + wr * 64 + ((lane >> 4) << 2);
#pragma unroll
    for (int n = 0; n < 4; n++) {
        const int gcol = col0 + wc * 64 + n * 16 + (lane & 15);
        const float bb = ball[gcol];
#pragma unroll
        for (int m = 0; m < 4; m++) {
#pragma unroll
            for (int r = 0; r < 4; r++) {
                const float val = acc[m][n][r] + bb;
                const int row = rb + m * 16 + r;
                if (gcol < 256) {
                    vbf[(size_t)row * 256 + gcol] = f2bf(val);
                } else {
                    const int oc = gcol - 256;
                    if (oc < 432)
                        ombf[(size_t)row * 432 + oc] = f2bf(val);
                }
            }
        }
    }
}

// ---------------------------------------------------------------------------
// FUSED deformable sampling + output GEMM + stats. One block per 8x8 px tile
// (256 blocks, 1/CU), 512 threads, ~158KB LDS.
//   Phase S: stage v halo tile (144x256 bf16) + om (64x432 bf16) via
//            global_load_lds (linear dest, per-lane clamped source).
//   Phase A: sampling (round-4 proven structure); each wave writes its row
//            into samp_s[64][256] bf16 with octet-XOR swizzle (oct ^= row&7):
//            row-uniform writes conflict-free, A-frag b128 reads 2-way (free).
//   Phase B: o[64x256] = samp @ WoutT^T + bout. 8 waves 2x4 (32x64 each),
//            K=256 in 8 steps; WoutT staged [oct][col] double-buffered via
//            global_load_lds (prefetch next buffer before compute).
//   Epilogue: bias + bf16 obf store + fused column stats -> psum[block][256].
// ---------------------------------------------------------------------------
__global__ __launch_bounds__(512) void dcn_out(
    const unsigned short* __restrict__ vbf,    // [n][4096][256] bf16
    const unsigned short* __restrict__ ombf,   // [m][432] bf16
    const unsigned short* __restrict__ WoutT,  // [256 cols][256 k] bf16
    const float* __restrict__ bias,
    unsigned short* __restrict__ obf,          // [m][256] bf16
    float* __restrict__ psum, float* __restrict__ psumsq)
{
    __shared__ unsigned short lds[80896];          // 161792 B
    unsigned short* v_s    = lds;                  // 36864 elems (144*256)
    unsigned short* om_s   = lds + 36864;          // 27648 elems (64*432)
    unsigned short* samp_s = lds + 64512;          // 16384 elems (64*256)
    unsigned short* Bs     = om_s;                 // overlay: 2 x 8192 elems
    float* ssum  = (float*)(om_s + 16384);         // 2 x 256 f32
    float* sqsum = ssum + 512;                     // 2 x 256 f32

    const int t = threadIdx.x;
    const int b = blockIdx.x;
    const int n   = b >> 6;
    const int py0 = ((b >> 3) & 7) * 8;
    const int px0 = (b & 7) * 8;
    const int y0t = py0 - 2, x0t = px0 - 2;

    // ---- Phase S: stage v tile (4608 x 16B) + om (3456 x 16B) ----
    {
        const unsigned short* vn = vbf + ((size_t)n << 12) * 256;
#pragma unroll
        for (int jj = 0; jj < 9; jj++) {
            const int j = jj * 512 + t;
            const int slot = j >> 5, wi = j & 31;
            const int ly = slot / 12, lx = slot - ly * 12;
            const int gy = min(max(y0t + ly, 0), 63);
            const int gx = min(max(x0t + lx, 0), 63);
            gload16(vn + (size_t)((gy << 6) + gx) * 256 + wi * 8, v_s + j * 8);
        }
#pragma unroll
        for (int jj = 0; jj < 7; jj++) {
            const int j = jj * 512 + t;
            if (j < 3456) {
                const int pl = j / 54, wi = j - pl * 54;
                const int m = (n << 12) + ((py0 + (pl >> 3)) << 6) + px0 + (pl & 7);
                gload16(ombf + (size_t)m * OMC + wi * 8, om_s + j * 8);
            }
        }
    }
    __syncthreads();

    const int lane = t & 63;
    const int wv   = t >> 6;           // wave id 0..7
    const int g    = lane >> 2;        // group 0..15
    const int cl   = lane & 3;         // channel quad
    const int choff = g * 16 + cl * 4;
    const int oct   = g * 2 + (cl >> 1);   // channel octet 0..31
    const int ohalf = (cl & 1) * 4;

    // ---- Phase A: sampling; write rows into samp_s (octet-XOR swizzle) ----
#pragma unroll 1
    for (int i = 0; i < 8; i++) {
        const int pl = wv * 8 + i;
        const int h  = py0 + (pl >> 3);
        const int w  = px0 + (pl & 7);
        const unsigned short* omr = om_s + pl * OMC + g * 27;
        float4 acc = make_float4(0.f, 0.f, 0.f, 0.f);
#pragma unroll
        for (int k = 0; k < 9; k++) {
            const float offy = bf2f(omr[2 * k]);
            const float offx = bf2f(omr[2 * k + 1]);
            const float mk   = bf2f(omr[18 + k]);
            const float sy = (float)(h + k / 3 - 1) + offy;
            const float sx = (float)(w + k % 3 - 1) + offx;
            const float y0f = floorf(sy), x0f = floorf(sx);
            const float fy = sy - y0f, fx = sx - x0f;
            const int y0 = (int)y0f, x0 = (int)x0f;
            const float ay  = ((unsigned)y0 < 64u) ? (1.f - fy) : 0.f;
            const float by  = ((unsigned)(y0 + 1) < 64u) ? fy : 0.f;
            const float axm = (((unsigned)x0 < 64u) ? (1.f - fx) : 0.f) * mk;
            const float bxm = (((unsigned)(x0 + 1) < 64u) ? fx : 0.f) * mk;
            const float w00 = ay * axm, w01 = ay * bxm;
            const float w10 = by * axm, w11 = by * bxm;
            const int ly = y0 - y0t, lx = x0 - x0t;
            if ((unsigned)ly <= 10u && (unsigned)lx <= 10u) {
                const unsigned short* p00 = v_s + ((ly * 12 + lx) * 256 + choff);
                acc4(p00,                  w00, acc);
                acc4(p00 + 256,            w01, acc);
                acc4(p00 + 12 * 256,       w10, acc);
                acc4(p00 + 12 * 256 + 256, w11, acc);
            } else {
                const int yc0 = min(max(y0, 0), 63), yc1 = min(max(y0 + 1, 0), 63);
                const int xc0 = min(max(x0, 0), 63), xc1 = min(max(x0 + 1, 0), 63);
                const unsigned short* vg = vbf + ((size_t)n << 12) * 256 + choff;
                acc4(vg + (size_t)((yc0 << 6) + xc0) * 256, w00, acc);
                acc4(vg + (size_t)((yc0 << 6) + xc1) * 256, w01, acc);
                acc4(vg + (size_t)((yc1 << 6) + xc0) * 256, w10, acc);
                acc4(vg + (size_t)((yc1 << 6) + xc1) * 256, w11, acc);
            }
        }
        const unsigned lo = (unsigned)f2bf(acc.x) | ((unsigned)f2bf(acc.y) << 16);
        const unsigned hi = (unsigned)f2bf(acc.z) | ((unsigned)f2bf(acc.w) << 16);
        *reinterpret_cast<uint2*>(samp_s + pl * 256 + ((oct ^ (pl & 7)) * 8) + ohalf)
            = make_uint2(lo, hi);
    }
    __syncthreads();   // sampling done; om_s region now reusable as Bs

    // ---- Phase B: GEMM [64x256] = samp_s @ WoutT^T ----
    const int wr = wv >> 2;   // 0..1
    const int wc = wv & 3;    // 0..3
    const int scol = t & 255;            // staging col
    const int soct = t >> 8;             // staging octet pair selector
    // prologue: stage buf0 (k0 = 0)
#pragma unroll
    for (int r = 0; r < 2; r++)
        gload16(WoutT + (size_t)scol * 256 + (r * 2 + soct) * 8,
                Bs + r * 4096 + t * 8);
    __syncthreads();

    f32x4 acc2[2][4];
#pragma unroll
    for (int mf = 0; mf < 2; mf++)
#pragma unroll
        for (int nf = 0; nf < 4; nf++) acc2[mf][nf] = (f32x4)0.f;

    for (int ks = 0; ks < 8; ks++) {
        if (ks < 7) {     // prefetch next buffer
            const int k0n = (ks + 1) * 32;
#pragma unroll
            for (int r = 0; r < 2; r++)
                gload16(WoutT + (size_t)scol * 256 + k0n + (r * 2 + soct) * 8,
                        Bs + ((ks + 1) & 1) * 8192 + r * 4096 + t * 8);
        }
        short8v a_[2], b_[4];
        const int k0o = ks * 4;
#pragma unroll
        for (int mf = 0; mf < 2; mf++) {
            const int row = wr * 32 + mf * 16 + (lane & 15);
            a_[mf] = *(const short8v*)(
                samp_s + row * 256 + ((k0o + (lane >> 4)) ^ (row & 7)) * 8);
        }
#pragma unroll
        for (int nf = 0; nf < 4; nf++) {
            const int col = wc * 64 + nf * 16 + (lane & 15);
            b_[nf] = *(const short8v*)(
                Bs + (ks & 1) * 8192 + (lane >> 4) * 2048 + col * 8);
        }
#pragma unroll
        for (int mf = 0; mf < 2; mf++)
#pragma unroll
            for (int nf = 0; nf < 4; nf++)
                acc2[mf][nf] = __builtin_amdgcn_mfma_f32_16x16x32_bf16(
                    a_[mf], b_[nf], acc2[mf][nf], 0, 0, 0);
        __syncthreads();
    }

    // ---- Epilogue: bias + obf store + fused stats ----
    const int rbl = wr * 32 + ((lane >> 4) << 2);
#pragma unroll
    for (int nf = 0; nf < 4; nf++) {
        const int col = wc * 64 + nf * 16 + (lane & 15);
        const float bb = bias[col];
        float s = 0.f, q = 0.f;
#pragma unroll
        for (int mf = 0; mf < 2; mf++) {
#pragma unroll
            for (int r = 0; r < 4; r++) {
                const float val = acc2[mf][nf][r] + bb;
                const int pl = rbl + mf * 16 + r;
                const int m = (n << 12) + ((py0 + (pl >> 3)) << 6) + px0 + (pl & 7);
                obf[(size_t)m * C2c + col] = f2bf(val);
                s += val; q += val * val;
            }
        }
        s += __shfl_xor(s, 16); s += __shfl_xor(s, 32);
        q += __shfl_xor(q, 16); q += __shfl_xor(q, 32);
        if (lane < 16) {
            ssum[wr * 256 + col]  = s;
            sqsum[wr * 256 + col] = q;
        }
    }
    __syncthreads();
    if (t < 256) {
        psum[(size_t)b * 256 + t]   = ssum[t] + ssum[256 + t];
        psumsq[(size_t)b * 256 + t] = sqsum[t] + sqsum[256 + t];
    }
}

__global__ __launch_bounds__(256) void stats2(
    const float* __restrict__ psum, const float* __restrict__ psumsq,
    float* __restrict__ meanp, float* __restrict__ rsigp)
{
    const int t = threadIdx.x;
    float s0 = 0.f, s1 = 0.f, s2_ = 0.f, s3 = 0.f;
    float q0 = 0.f, q1 = 0.f, q2 = 0.f, q3 = 0.f;
    for (int b = 0; b < 256; b += 4) {
        s0  += psum[(b + 0) * 256 + t];   q0 += psumsq[(b + 0) * 256 + t];
        s1  += psum[(b + 1) * 256 + t];   q1 += psumsq[(b + 1) * 256 + t];
        s2_ += psum[(b + 2) * 256 + t];   q2 += psumsq[(b + 2) * 256 + t];
        s3  += psum[(b + 3) * 256 + t];   q3 += psumsq[(b + 3) * 256 + t];
    }
    const float s = (s0 + s1) + (s2_ + s3);
    const float q = (q0 + q1) + (q2 + q3);
    const float inv = 1.f / (float)Mrows;
    const float mean = s * inv;
    const float var  = q * inv - mean * mean;
    meanp[t] = mean;
    rsigp[t] = rsqrtf(var + EPSc);
}

// ---------------------------------------------------------------------------
// Normalize + SiLU + NHWC->NCHW transpose. o is bf16. 64px x 64ch per block.
// ---------------------------------------------------------------------------
__global__ __launch_bounds__(256) void norm_silu_transpose(
    const unsigned short* __restrict__ obf, const float* __restrict__ meanp,
    const float* __restrict__ rsigp, const float* __restrict__ gamma,
    const float* __restrict__ beta, float* __restrict__ out)
{
    __shared__ float tile[64][65];
    const int tid = threadIdx.x;
    const int p0 = blockIdx.x * 64;
    const int c0 = blockIdx.y * 64;
    const int n  = blockIdx.z;
    const int m0 = n * HWc + p0;
    {
#pragma unroll
        for (int i = 0; i < 8; i++) {
            const int idx = i * 256 + tid;
            const int p  = idx >> 5;
            const int cp = (idx & 31) * 2;
            const unsigned u = *reinterpret_cast<const unsigned*>(
                obf + (size_t)(m0 + p) * C2c + c0 + cp);
            tile[p][cp]     = __builtin_bit_cast(float, u << 16);
            tile[p][cp + 1] = __builtin_bit_cast(float, u & 0xffff0000u);
        }
    }
    __syncthreads();
    {
        const int lp = tid & 63, lcq = tid >> 6;
#pragma unroll
        for (int i = 0; i < 16; i++) {
            const int c  = lcq * 16 + i;
            const int ch = c0 + c;
            const float x = tile[lp][c];
            const float y = gamma[ch] * (x - meanp[ch]) * rsigp[ch] + beta[ch];
            const float sy = y / (1.f + expf(-y));
            out[(size_t)n * C2c * HWc + (size_t)ch * HWc + p0 + lp] = sy;
        }
    }
}

// ---------------------------------------------------------------------------
extern "C" void kernel_launch(void* const* d_in, const int* in_sizes, int n_in,
                              void* d_out, int out_size, void* d_ws, size_t ws_size,
                              hipStream_t stream)
{
    const float* x     = (const float*)d_in[0];
    const float* Wv    = (const float*)d_in[1];
    const float* bv    = (const float*)d_in[2];
    const float* Wom   = (const float*)d_in[3];
    const float* bom   = (const float*)d_in[4];
    const float* Wout  = (const float*)d_in[5];
    const float* bout  = (const float*)d_in[6];
    const float* gamma = (const float*)d_in[7];
    const float* beta  = (const float*)d_in[8];
    float* out = (float*)d_out;

    unsigned short* us = (unsigned short*)d_ws;
    unsigned short* Ax    = us;                    // 4,194,304
    unsigned short* vbf   = Ax + 4194304;          // 4,194,304
    unsigned short* ombf  = vbf + 4194304;         // 7,077,888
    unsigned short* obf   = ombf + 7077888;        // 4,194,304
    unsigned short* WallT = obf + 4194304;         // 196,608
    unsigned short* WoutT = WallT + 196608;        // 65,536
    float* fs     = (float*)(WoutT + 65536);
    float* psum   = fs;                            // 65,536
    float* psumsq = psum + 65536;                  // 65,536
    float* meanp  = psumsq + 65536;
    float* rsigp  = meanp + 256;
    float* ball   = rsigp + 256;                   // 768

    // fused conversions (x transpose + weights)
    prep<<<2051, 256, 0, stream>>>(x, Wv, Wom, Wout, bv, bom,
                                   Ax, WallT, WoutT, ball);
    // v (cols 0..255) + om (cols 256..687) in one GEMM, XCD-swizzled
    gemm_vom<<<dim3(3, 128), 512, 0, stream>>>(Ax, WallT, ball, vbf, ombf);
    // fused sampling + output GEMM + stats
    dcn_out<<<256, 512, 0, stream>>>(vbf, ombf, WoutT, bout, obf, psum, psumsq);
    stats2<<<1, 256, 0, stream>>>(psum, psumsq, meanp, rsigp);
    norm_silu_transpose<<<dim3(64, 4, 4), 256, 0, stream>>>(obf, meanp, rsigp,
                                                            gamma, beta, out);
}

// Round 8
// 72.409 us; speedup vs baseline: 1.0939x; 1.0939x over previous
//
#include <hip/hip_runtime.h>
#include <hip/hip_bf16.h>
#include <math.h>

// Problem constants
constexpr int Nimg = 4;
constexpr int Cin  = 256;
constexpr int Hc   = 64;
constexpr int Wc   = 64;
constexpr int HWc  = Hc * Wc;          // 4096
constexpr int Mrows = Nimg * HWc;      // 16384
constexpr int Gg   = 16;
constexpr int K2c  = 9;
constexpr int OMC  = Gg * K2c * 3;     // 432
constexpr int C2c  = 256;
constexpr float EPSc = 1e-5f;

typedef __attribute__((ext_vector_type(8))) short short8v;   // 8 bf16 bits
typedef __attribute__((ext_vector_type(4))) float f32x4;

__device__ __forceinline__ unsigned short f2bf(float f) {
    return __builtin_bit_cast(unsigned short, __float2bfloat16(f));
}
__device__ __forceinline__ float bf2f(unsigned short u) {
    return __builtin_bit_cast(float, (unsigned)u << 16);
}

__device__ __forceinline__ void gload16(const unsigned short* g, unsigned short* l) {
    __builtin_amdgcn_global_load_lds(
        (const __attribute__((address_space(1))) void*)g,
        (__attribute__((address_space(3))) void*)l, 16, 0, 0);
}

// Accumulate 4 bf16 channels (8B at p) with weight wk into acc.
__device__ __forceinline__ void acc4(const unsigned short* p, float wk, float4& a) {
    const uint2 u = *reinterpret_cast<const uint2*>(p);
    a.x += wk * __builtin_bit_cast(float, u.x << 16);
    a.y += wk * __builtin_bit_cast(float, u.x & 0xffff0000u);
    a.z += wk * __builtin_bit_cast(float, u.y << 16);
    a.w += wk * __builtin_bit_cast(float, u.y & 0xffff0000u);
}

// ---------------------------------------------------------------------------
// Fused prep: blocks [0,1024) transpose+convert x (NCHW fp32 -> A[m][k] bf16);
// blocks [1024,2051) convert weights to transposed bf16 + concat bias.
// ---------------------------------------------------------------------------
__global__ __launch_bounds__(256) void prep(
    const float* __restrict__ x,
    const float* __restrict__ Wv, const float* __restrict__ Wom,
    const float* __restrict__ Wout,
    const float* __restrict__ bv, const float* __restrict__ bom,
    unsigned short* __restrict__ A,
    unsigned short* __restrict__ WallT, unsigned short* __restrict__ WoutT,
    float* __restrict__ ball)
{
    __shared__ float tile[64][65];
    const int t   = threadIdx.x;
    const int bid = blockIdx.x;
    if (bid < 1024) {
        const int p0 = (bid & 63) * 64;
        const int c0 = ((bid >> 6) & 3) * 64;
        const int n  = bid >> 8;
        const float* xb = x + ((size_t)n * Cin + c0) * HWc + p0;
#pragma unroll
        for (int i = 0; i < 16; i++) {
            const int c = i * 4 + (t >> 6);
            tile[c][t & 63] = xb[(size_t)c * HWc + (t & 63)];
        }
        __syncthreads();
        unsigned short* Ab = A + ((size_t)(n * HWc) + p0) * Cin + c0;
#pragma unroll
        for (int i = 0; i < 8; i++) {
            const int p  = i * 8 + (t >> 5);
            const int c2 = (t & 31) * 2;
            const unsigned lo = f2bf(tile[c2][p]);
            const unsigned hi = f2bf(tile[c2 + 1][p]);
            *(unsigned*)(Ab + (size_t)p * Cin + c2) = lo | (hi << 16);
        }
        return;
    }
    const int e = (bid - 1024) * 256 + t;
    if (e < 65536) {                       // Wv -> WallT rows 0..255
        const int nc = e >> 8, k = e & 255;
        WallT[e] = f2bf(Wv[(size_t)k * 256 + nc]);
    } else if (e < 196608) {               // Wom -> WallT rows 256..767 (pad)
        const int e2 = e - 65536;
        const int nc = e2 >> 8, k = e2 & 255;
        WallT[e] = f2bf(nc < 432 ? Wom[(size_t)k * 432 + nc] : 0.f);
    } else if (e < 262144) {               // Wout -> WoutT
        const int e3 = e - 196608;
        const int nc = e3 >> 8, k = e3 & 255;
        WoutT[e3] = f2bf(Wout[(size_t)k * 256 + nc]);
    } else if (e < 262912) {               // concat bias
        const int i = e - 262144;
        ball[i] = (i < 256) ? bv[i] : ((i < 688) ? bom[i - 256] : 0.f);
    }
}

// ---------------------------------------------------------------------------
// Fused v+om GEMM: [16384 x 768] = A[16384 x 256] @ WallT[768 x 256]^T + ball.
// 128x256 tile, BK=32, 8 waves (2x4). XCD-swizzled.
// ---------------------------------------------------------------------------
__global__ __launch_bounds__(512) void gemm_vom(
    const unsigned short* __restrict__ A,
    const unsigned short* __restrict__ Bt,
    const float* __restrict__ ball,
    unsigned short* __restrict__ vbf,
    unsigned short* __restrict__ ombf)
{
    __shared__ unsigned short As[128 * 32];
    __shared__ unsigned short Bs[256 * 32];
    const int t    = threadIdx.x;
    const int lane = t & 63;
    const int wid  = t >> 6;
    const int wr   = wid >> 2;
    const int wc   = wid & 3;
    const int vid = blockIdx.x + 3 * blockIdx.y;
    const int xcd = vid & 7;
    const int j8  = vid >> 3;             // 0..47
    const int row0 = (xcd * 16 + j8 / 3) * 128;
    const int col0 = (j8 % 3) * 256;

    f32x4 acc[4][4];
#pragma unroll
    for (int m = 0; m < 4; m++)
#pragma unroll
        for (int n = 0; n < 4; n++) acc[m][n] = (f32x4)0.f;

    const int r0   = t >> 2;
    const int koff = (t & 3) * 8;
    const unsigned short* gA  = A  + (size_t)(row0 + r0) * 256 + koff;
    const unsigned short* gB0 = Bt + (size_t)(col0 + r0) * 256 + koff;
    const unsigned short* gB1 = Bt + (size_t)(col0 + 128 + r0) * 256 + koff;
    const int sbase = wid * 512;

    const int arow = wr * 64 + (lane & 15);
    const int bcol = wc * 64 + (lane & 15);
    const int kq   = (lane >> 4) * 8;

    for (int k0 = 0; k0 < 256; k0 += 32) {
        gload16(gA  + k0, As + sbase);
        gload16(gB0 + k0, Bs + sbase);
        gload16(gB1 + k0, Bs + 4096 + sbase);
        __syncthreads();

        short8v a_[4], b_[4];
#pragma unroll
        for (int m = 0; m < 4; m++)
            a_[m] = *(const short8v*)(As + (arow + m * 16) * 32 + kq);
#pragma unroll
        for (int n = 0; n < 4; n++)
            b_[n] = *(const short8v*)(Bs + (bcol + n * 16) * 32 + kq);
#pragma unroll
        for (int m = 0; m < 4; m++)
#pragma unroll
            for (int n = 0; n < 4; n++)
                acc[m][n] = __builtin_amdgcn_mfma_f32_16x16x32_bf16(
                    a_[m], b_[n], acc[m][n], 0, 0, 0);
        __syncthreads();
    }

    const int rb = row0 + wr * 64 + ((lane >> 4) << 2);
#pragma unroll
    for (int n = 0; n < 4; n++) {
        const int gcol = col0 + wc * 64 + n * 16 + (lane & 15);
        const float bb = ball[gcol];
#pragma unroll
        for (int m = 0; m < 4; m++) {
#pragma unroll
            for (int r = 0; r < 4; r++) {
                const float val = acc[m][n][r] + bb;
                const int row = rb + m * 16 + r;
                if (gcol < 256) {
                    vbf[(size_t)row * 256 + gcol] = f2bf(val);
                } else {
                    const int oc = gcol - 256;
                    if (oc < 432)
                        ombf[(size_t)row * 432 + oc] = f2bf(val);
                }
            }
        }
    }
}

// ---------------------------------------------------------------------------
// Deformable sampling, LDS-tiled + channel-split (round-6 proven structure),
// staging via global_load_lds (wave-uniform dest, per-lane clamped source;
// guard boundaries fall on whole waves: 2304=4.5*512, 1728=3*512+3*64).
// 64.5KB LDS -> 2 blocks/CU.
// ---------------------------------------------------------------------------
__global__ __launch_bounds__(512) void dcn_sample(
    const unsigned short* __restrict__ vbf,    // [n][4096][256] bf16
    const unsigned short* __restrict__ ombf,   // [m][432] bf16
    unsigned short* __restrict__ sampled)      // [m][256] bf16
{
    __shared__ unsigned short v_s[144 * 128];  // 36864 B
    __shared__ unsigned short om_s[64 * 216];  // 27648 B
    const int t = threadIdx.x;
    const int b = blockIdx.x;
    const int chalf = b & 1;
    const int tile  = b >> 1;
    const int n   = tile >> 6;
    const int py0 = ((tile >> 3) & 7) * 8;
    const int px0 = (tile & 7) * 8;
    const int y0t = py0 - 2, x0t = px0 - 2;
    const int wub = t & ~63;                   // wave-uniform thread base

    {   // stage v half-tile: 144 slots x 128ch = 2304 uint4 (16B each)
        const unsigned short* vn = vbf + ((size_t)n << 12) * 256 + chalf * 128;
#pragma unroll
        for (int jj = 0; jj < 5; jj++) {
            const int j = jj * 512 + t;
            if (j < 2304) {
                const int slot = j >> 4, wi = j & 15;
                const int ly = slot / 12, lx = slot - ly * 12;
                const int gy = min(max(y0t + ly, 0), 63);
                const int gx = min(max(x0t + lx, 0), 63);
                gload16(vn + (size_t)((gy << 6) + gx) * 256 + wi * 8,
                        v_s + (size_t)(jj * 512 + wub) * 8);
            }
        }
        // stage om half: 64 px x 216 bf16 = 1728 uint4
#pragma unroll
        for (int jj = 0; jj < 4; jj++) {
            const int j = jj * 512 + t;
            if (j < 1728) {
                const int pl = j / 27, wi = j - pl * 27;
                const int m = (n << 12) + ((py0 + (pl >> 3)) << 6) + px0 + (pl & 7);
                gload16(ombf + (size_t)m * OMC + chalf * 216 + wi * 8,
                        om_s + (size_t)(jj * 512 + wub) * 8);
            }
        }
    }
    __syncthreads();

    const int lane  = t & 63;
    const int wv    = t >> 6;            // wave id 0..7
    const int pxsel = lane >> 5;         // 0..1
    const int g     = (lane >> 2) & 7;   // local group 0..7
    const int cl    = lane & 3;
    const int chl   = g * 16 + cl * 4;   // local channel 0..127

#pragma unroll 1
    for (int i = 0; i < 4; i++) {
        const int pl = wv * 8 + i * 2 + pxsel;
        const int h  = py0 + (pl >> 3);
        const int w  = px0 + (pl & 7);
        const unsigned short* omr = om_s + pl * 216 + g * 27;
        float4 acc = make_float4(0.f, 0.f, 0.f, 0.f);
#pragma unroll
        for (int k = 0; k < 9; k++) {
            const float offy = bf2f(omr[2 * k]);
            const float offx = bf2f(omr[2 * k + 1]);
            const float mk   = bf2f(omr[18 + k]);
            const float sy = (float)(h + k / 3 - 1) + offy;
            const float sx = (float)(w + k % 3 - 1) + offx;
            const float y0f = floorf(sy), x0f = floorf(sx);
            const float fy = sy - y0f, fx = sx - x0f;
            const int y0 = (int)y0f, x0 = (int)x0f;
            const float ay  = ((unsigned)y0 < 64u) ? (1.f - fy) : 0.f;
            const float by  = ((unsigned)(y0 + 1) < 64u) ? fy : 0.f;
            const float axm = (((unsigned)x0 < 64u) ? (1.f - fx) : 0.f) * mk;
            const float bxm = (((unsigned)(x0 + 1) < 64u) ? fx : 0.f) * mk;
            const float w00 = ay * axm, w01 = ay * bxm;
            const float w10 = by * axm, w11 = by * bxm;
            const int ly = y0 - y0t, lx = x0 - x0t;
            if ((unsigned)ly <= 10u && (unsigned)lx <= 10u) {
                const unsigned short* p00 = v_s + ((ly * 12 + lx) * 128 + chl);
                acc4(p00,                  w00, acc);
                acc4(p00 + 128,            w01, acc);
                acc4(p00 + 12 * 128,       w10, acc);
                acc4(p00 + 12 * 128 + 128, w11, acc);
            } else {
                const int yc0 = min(max(y0, 0), 63), yc1 = min(max(y0 + 1, 0), 63);
                const int xc0 = min(max(x0, 0), 63), xc1 = min(max(x0 + 1, 0), 63);
                const unsigned short* vg =
                    vbf + ((size_t)n << 12) * 256 + chalf * 128 + chl;
                acc4(vg + (size_t)((yc0 << 6) + xc0) * 256, w00, acc);
                acc4(vg + (size_t)((yc0 << 6) + xc1) * 256, w01, acc);
                acc4(vg + (size_t)((yc1 << 6) + xc0) * 256, w10, acc);
                acc4(vg + (size_t)((yc1 << 6) + xc1) * 256, w11, acc);
            }
        }
        const int m = (n << 12) + (h << 6) + w;
        const unsigned lo = (unsigned)f2bf(acc.x) | ((unsigned)f2bf(acc.y) << 16);
        const unsigned hi = (unsigned)f2bf(acc.z) | ((unsigned)f2bf(acc.w) << 16);
        *reinterpret_cast<uint2*>(sampled + (size_t)m * 256 + chalf * 128 + chl)
            = make_uint2(lo, hi);
    }
}

// ---------------------------------------------------------------------------
// Output GEMM + fused per-block channel stats. o stored bf16; stats from fp32.
// 128x128 tile, BK=32, 4 waves (2x2). XCD-swizzled.
// ---------------------------------------------------------------------------
__global__ __launch_bounds__(256) void gemm_out(
    const unsigned short* __restrict__ A,
    const unsigned short* __restrict__ Bt,
    const float* __restrict__ bias,
    unsigned short* __restrict__ obf,
    float* __restrict__ psum, float* __restrict__ psumsq)
{
    __shared__ unsigned short As[128 * 32];
    __shared__ unsigned short Bs[128 * 32];
    __shared__ float ssum[2][128];
    __shared__ float sqsum[2][128];
    const int t    = threadIdx.x;
    const int lane = t & 63;
    const int wr   = (t >> 7);
    const int wc   = (t >> 6) & 1;
    const int vid = blockIdx.x + 2 * blockIdx.y;
    const int xcd = vid & 7;
    const int j8  = vid >> 3;             // 0..31
    const int by   = xcd * 16 + (j8 >> 1);
    const int row0 = by * 128;
    const int col0 = (j8 & 1) * 128;

    f32x4 acc[4][4];
#pragma unroll
    for (int m = 0; m < 4; m++)
#pragma unroll
        for (int n = 0; n < 4; n++) acc[m][n] = (f32x4)0.f;

    const int r0   = t >> 2;
    const int koff = (t & 3) * 8;
    const unsigned short* gA = A  + (size_t)(row0 + r0) * 256 + koff;
    const unsigned short* gB = Bt + (size_t)(col0 + r0) * 256 + koff;
    const int wbase = (t & 192) * 8;

    const int aoff = ((wr * 64) + (lane & 15)) * 32 + (lane >> 4) * 8;
    const int boff = ((wc * 64) + (lane & 15)) * 32 + (lane >> 4) * 8;

    for (int k0 = 0; k0 < 256; k0 += 32) {
        gload16(gA + k0,            As + wbase);
        gload16(gA + k0 + 64 * 256, As + 2048 + wbase);
        gload16(gB + k0,            Bs + wbase);
        gload16(gB + k0 + 64 * 256, Bs + 2048 + wbase);
        __syncthreads();

        short8v a_[4], b_[4];
#pragma unroll
        for (int m = 0; m < 4; m++)
            a_[m] = *(const short8v*)(As + aoff + m * 16 * 32);
#pragma unroll
        for (int n = 0; n < 4; n++)
            b_[n] = *(const short8v*)(Bs + boff + n * 16 * 32);
#pragma unroll
        for (int m = 0; m < 4; m++)
#pragma unroll
            for (int n = 0; n < 4; n++)
                acc[m][n] = __builtin_amdgcn_mfma_f32_16x16x32_bf16(
                    a_[m], b_[n], acc[m][n], 0, 0, 0);
        __syncthreads();
    }

    const int rbase = row0 + wr * 64 + ((lane >> 4) << 2);
    const int cloc  = wc * 64 + (lane & 15);
#pragma unroll
    for (int n = 0; n < 4; n++) {
        const int col = col0 + cloc + n * 16;
        const float bb = bias[col];
        float s = 0.f, q = 0.f;
#pragma unroll
        for (int m = 0; m < 4; m++) {
#pragma unroll
            for (int r = 0; r < 4; r++) {
                const float val = acc[m][n][r] + bb;
                obf[(size_t)(rbase + m * 16 + r) * C2c + col] = f2bf(val);
                s += val; q += val * val;
            }
        }
        s += __shfl_xor(s, 16); s += __shfl_xor(s, 32);
        q += __shfl_xor(q, 16); q += __shfl_xor(q, 32);
        if (lane < 16) {
            ssum[wr][cloc + n * 16]  = s;
            sqsum[wr][cloc + n * 16] = q;
        }
    }
    __syncthreads();
    if (t < 128) {
        psum[(size_t)by * 256 + col0 + t]   = ssum[0][t] + ssum[1][t];
        psumsq[(size_t)by * 256 + col0 + t] = sqsum[0][t] + sqsum[1][t];
    }
}

// ---------------------------------------------------------------------------
// Fused stats finalize + normalize + SiLU + NHWC->NCHW transpose.
// Grid (16,4,4): block covers 256 px x 64 ch (4 sub-tiles of 64px).
// Stats: each block redundantly reduces psum[128][its 64 ch] (L2-resident,
// deterministic fixed-order) -> no separate stats2 launch.
// ---------------------------------------------------------------------------
__global__ __launch_bounds__(256) void norm_silu_transpose(
    const unsigned short* __restrict__ obf,
    const float* __restrict__ psum, const float* __restrict__ psumsq,
    const float* __restrict__ gamma, const float* __restrict__ beta,
    float* __restrict__ out)
{
    __shared__ float tile[64][65];
    __shared__ float sp[4][64], sq[4][64], meanv[64], rsigv[64];
    const int t  = threadIdx.x;
    const int c0 = blockIdx.y * 64;
    const int n  = blockIdx.z;
    const int pb = blockIdx.x * 256;

    // ---- stats prelude: 128-row reduce for this block's 64 channels ----
    {
        const int lc = t & 63, rq = t >> 6;
        float s = 0.f, q = 0.f;
        const float* ps = psum   + (size_t)(rq * 32) * 256 + c0 + lc;
        const float* pq = psumsq + (size_t)(rq * 32) * 256 + c0 + lc;
#pragma unroll 4
        for (int r = 0; r < 32; r++) {
            s += ps[(size_t)r * 256];
            q += pq[(size_t)r * 256];
        }
        sp[rq][lc] = s; sq[rq][lc] = q;
    }
    __syncthreads();
    if (t < 64) {
        const float ss = (sp[0][t] + sp[1][t]) + (sp[2][t] + sp[3][t]);
        const float qq = (sq[0][t] + sq[1][t]) + (sq[2][t] + sq[3][t]);
        const float inv = 1.f / (float)Mrows;
        const float mean = ss * inv;
        const float var  = qq * inv - mean * mean;
        meanv[t] = mean;
        rsigv[t] = rsqrtf(var + EPSc);
    }
    __syncthreads();

    const int lp = t & 63, lcq = t >> 6;
    float gv[16], bvv[16];
#pragma unroll
    for (int i = 0; i < 16; i++) {
        gv[i]  = gamma[c0 + lcq * 16 + i];
        bvv[i] = beta[c0 + lcq * 16 + i];
    }

#pragma unroll 1
    for (int st = 0; st < 4; st++) {
        const int p0 = pb + st * 64;
        const int m0 = n * HWc + p0;
#pragma unroll
        for (int i = 0; i < 8; i++) {
            const int idx = i * 256 + t;
            const int p  = idx >> 5;
            const int cp = (idx & 31) * 2;
            const unsigned u = *reinterpret_cast<const unsigned*>(
                obf + (size_t)(m0 + p) * C2c + c0 + cp);
            tile[p][cp]     = __builtin_bit_cast(float, u << 16);
            tile[p][cp + 1] = __builtin_bit_cast(float, u & 0xffff0000u);
        }
        __syncthreads();
#pragma unroll
        for (int i = 0; i < 16; i++) {
            const int c  = lcq * 16 + i;
            const int ch = c0 + c;
            const float x = tile[lp][c];
            const float y = gv[i] * (x - meanv[c]) * rsigv[c] + bvv[i];
            const float sy = y / (1.f + expf(-y));
            out[(size_t)n * C2c * HWc + (size_t)ch * HWc + p0 + lp] = sy;
        }
        __syncthreads();
    }
}

// ---------------------------------------------------------------------------
extern "C" void kernel_launch(void* const* d_in, const int* in_sizes, int n_in,
                              void* d_out, int out_size, void* d_ws, size_t ws_size,
                              hipStream_t stream)
{
    const float* x     = (const float*)d_in[0];
    const float* Wv    = (const float*)d_in[1];
    const float* bv    = (const float*)d_in[2];
    const float* Wom   = (const float*)d_in[3];
    const float* bom   = (const float*)d_in[4];
    const float* Wout  = (const float*)d_in[5];
    const float* bout  = (const float*)d_in[6];
    const float* gamma = (const float*)d_in[7];
    const float* beta  = (const float*)d_in[8];
    float* out = (float*)d_out;

    unsigned short* us = (unsigned short*)d_ws;
    unsigned short* Ax    = us;                    // 4,194,304
    unsigned short* vbf   = Ax + 4194304;          // 4,194,304
    unsigned short* ombf  = vbf + 4194304;         // 7,077,888
    unsigned short* samp  = ombf + 7077888;        // 4,194,304
    unsigned short* obf   = samp + 4194304;        // 4,194,304
    unsigned short* WallT = obf + 4194304;         // 196,608
    unsigned short* WoutT = WallT + 196608;        // 65,536
    float* fs     = (float*)(WoutT + 65536);
    float* psum   = fs;                            // 32,768
    float* psumsq = psum + 32768;                  // 32,768
    float* ball   = psumsq + 32768;                // 768

    // fused conversions (x transpose + weights)
    prep<<<2051, 256, 0, stream>>>(x, Wv, Wom, Wout, bv, bom,
                                   Ax, WallT, WoutT, ball);
    // v (cols 0..255) + om (cols 256..687) in one GEMM, XCD-swizzled
    gemm_vom<<<dim3(3, 128), 512, 0, stream>>>(Ax, WallT, ball, vbf, ombf);
    // deformable sampling (LDS-tiled, channel-split, gload16 staging)
    dcn_sample<<<512, 512, 0, stream>>>(vbf, ombf, samp);
    // o = sampled @ Wout + bout -> bf16, with fused per-block channel stats
    gemm_out<<<dim3(2, 128), 256, 0, stream>>>(samp, WoutT, bout, obf, psum, psumsq);
    // fused stats finalize + normalize + SiLU + transpose
    norm_silu_transpose<<<dim3(16, 4, 4), 256, 0, stream>>>(obf, psum, psumsq,
                                                            gamma, beta, out);
}

// Round 9
// 72.084 us; speedup vs baseline: 1.0989x; 1.0045x over previous
//
#include <hip/hip_runtime.h>
#include <hip/hip_bf16.h>
#include <math.h>

// Problem constants
constexpr int Nimg = 4;
constexpr int Cin  = 256;
constexpr int Hc   = 64;
constexpr int Wc   = 64;
constexpr int HWc  = Hc * Wc;          // 4096
constexpr int Mrows = Nimg * HWc;      // 16384
constexpr int Gg   = 16;
constexpr int K2c  = 9;
constexpr int OMC  = Gg * K2c * 3;     // 432
constexpr int C2c  = 256;
constexpr float EPSc = 1e-5f;

typedef __attribute__((ext_vector_type(8))) short short8v;   // 8 bf16 bits
typedef __attribute__((ext_vector_type(4))) float f32x4;

__device__ __forceinline__ unsigned short f2bf(float f) {
    return __builtin_bit_cast(unsigned short, __float2bfloat16(f));
}
__device__ __forceinline__ float bf2f(unsigned short u) {
    return __builtin_bit_cast(float, (unsigned)u << 16);
}

__device__ __forceinline__ void gload16(const unsigned short* g, unsigned short* l) {
    __builtin_amdgcn_global_load_lds(
        (const __attribute__((address_space(1))) void*)g,
        (__attribute__((address_space(3))) void*)l, 16, 0, 0);
}

// Accumulate 4 bf16 channels (8B at p) with weight wk into acc.
__device__ __forceinline__ void acc4(const unsigned short* p, float wk, float4& a) {
    const uint2 u = *reinterpret_cast<const uint2*>(p);
    a.x += wk * __builtin_bit_cast(float, u.x << 16);
    a.y += wk * __builtin_bit_cast(float, u.x & 0xffff0000u);
    a.z += wk * __builtin_bit_cast(float, u.y << 16);
    a.w += wk * __builtin_bit_cast(float, u.y & 0xffff0000u);
}

// ---------------------------------------------------------------------------
// Fused prep: blocks [0,1024) transpose+convert x (NCHW fp32 -> A[m][k] bf16),
// float4 global reads (4 insts/wave instead of 16);
// blocks [1024,2051) convert weights to transposed bf16 + concat bias.
// ---------------------------------------------------------------------------
__global__ __launch_bounds__(256) void prep(
    const float* __restrict__ x,
    const float* __restrict__ Wv, const float* __restrict__ Wom,
    const float* __restrict__ Wout,
    const float* __restrict__ bv, const float* __restrict__ bom,
    unsigned short* __restrict__ A,
    unsigned short* __restrict__ WallT, unsigned short* __restrict__ WoutT,
    float* __restrict__ ball)
{
    __shared__ float tile[64][65];
    const int t   = threadIdx.x;
    const int bid = blockIdx.x;
    if (bid < 1024) {
        const int p0 = (bid & 63) * 64;
        const int c0 = ((bid >> 6) & 3) * 64;
        const int n  = bid >> 8;
        const float* xb = x + ((size_t)n * Cin + c0) * HWc + p0;
        // float4 over px: 16 lanes x 4px = 64px per channel, 16 ch per pass
        {
            const int cl = t >> 4;          // channel within pass group
            const int p4 = (t & 15) * 4;
#pragma unroll
            for (int i = 0; i < 4; i++) {
                const int c = i * 16 + cl;
                const float4 f = *reinterpret_cast<const float4*>(
                    xb + (size_t)c * HWc + p4);
                tile[c][p4 + 0] = f.x;
                tile[c][p4 + 1] = f.y;
                tile[c][p4 + 2] = f.z;
                tile[c][p4 + 3] = f.w;
            }
        }
        __syncthreads();
        unsigned short* Ab = A + ((size_t)(n * HWc) + p0) * Cin + c0;
#pragma unroll
        for (int i = 0; i < 8; i++) {
            const int p  = i * 8 + (t >> 5);
            const int c2 = (t & 31) * 2;
            const unsigned lo = f2bf(tile[c2][p]);
            const unsigned hi = f2bf(tile[c2 + 1][p]);
            *(unsigned*)(Ab + (size_t)p * Cin + c2) = lo | (hi << 16);
        }
        return;
    }
    const int e = (bid - 1024) * 256 + t;
    if (e < 65536) {                       // Wv -> WallT rows 0..255
        const int nc = e >> 8, k = e & 255;
        WallT[e] = f2bf(Wv[(size_t)k * 256 + nc]);
    } else if (e < 196608) {               // Wom -> WallT rows 256..767 (pad)
        const int e2 = e - 65536;
        const int nc = e2 >> 8, k = e2 & 255;
        WallT[e] = f2bf(nc < 432 ? Wom[(size_t)k * 432 + nc] : 0.f);
    } else if (e < 262144) {               // Wout -> WoutT
        const int e3 = e - 196608;
        const int nc = e3 >> 8, k = e3 & 255;
        WoutT[e3] = f2bf(Wout[(size_t)k * 256 + nc]);
    } else if (e < 262912) {               // concat bias
        const int i = e - 262144;
        ball[i] = (i < 256) ? bv[i] : ((i < 688) ? bom[i - 256] : 0.f);
    }
}

// ---------------------------------------------------------------------------
// Fused v+om GEMM: [16384 x 768] = A[16384 x 256] @ WallT[768 x 256]^T + ball.
// 128x128 tile, BK=32, 4 waves (2x2). Grid 6x128 = 768 blocks = exactly
// 3 blocks/CU (no block-tail). XCD swizzle: each XCD gets 16 row-blocks x 6
// col-tiles contiguously -> A panel (1MB) L2-resident across col re-reads.
// ---------------------------------------------------------------------------
__global__ __launch_bounds__(256) void gemm_vom(
    const unsigned short* __restrict__ A,
    const unsigned short* __restrict__ Bt,
    const float* __restrict__ ball,
    unsigned short* __restrict__ vbf,
    unsigned short* __restrict__ ombf)
{
    __shared__ unsigned short As[128 * 32];
    __shared__ unsigned short Bs[128 * 32];
    const int t    = threadIdx.x;
    const int lane = t & 63;
    const int wr   = (t >> 7);
    const int wc   = (t >> 6) & 1;
    const int vid = blockIdx.x + 6 * blockIdx.y;   // 0..767
    const int xcd = vid & 7;
    const int j8  = vid >> 3;                      // 0..95
    const int row0 = (xcd * 16 + j8 / 6) * 128;
    const int col0 = (j8 % 6) * 128;

    f32x4 acc[4][4];
#pragma unroll
    for (int m = 0; m < 4; m++)
#pragma unroll
        for (int n = 0; n < 4; n++) acc[m][n] = (f32x4)0.f;

    const int r0   = t >> 2;
    const int koff = (t & 3) * 8;
    const unsigned short* gA = A  + (size_t)(row0 + r0) * 256 + koff;
    const unsigned short* gB = Bt + (size_t)(col0 + r0) * 256 + koff;
    const int wbase = (t & 192) * 8;

    const int aoff = ((wr * 64) + (lane & 15)) * 32 + (lane >> 4) * 8;
    const int boff = ((wc * 64) + (lane & 15)) * 32 + (lane >> 4) * 8;

    for (int k0 = 0; k0 < 256; k0 += 32) {
        gload16(gA + k0,            As + wbase);
        gload16(gA + k0 + 64 * 256, As + 2048 + wbase);
        gload16(gB + k0,            Bs + wbase);
        gload16(gB + k0 + 64 * 256, Bs + 2048 + wbase);
        __syncthreads();

        short8v a_[4], b_[4];
#pragma unroll
        for (int m = 0; m < 4; m++)
            a_[m] = *(const short8v*)(As + aoff + m * 16 * 32);
#pragma unroll
        for (int n = 0; n < 4; n++)
            b_[n] = *(const short8v*)(Bs + boff + n * 16 * 32);
#pragma unroll
        for (int m = 0; m < 4; m++)
#pragma unroll
            for (int n = 0; n < 4; n++)
                acc[m][n] = __builtin_amdgcn_mfma_f32_16x16x32_bf16(
                    a_[m], b_[n], acc[m][n], 0, 0, 0);
        __syncthreads();
    }

    const int rb = row0 + wr * 64 + ((lane >> 4) << 2);
#pragma unroll
    for (int n = 0; n < 4; n++) {
        const int gcol = col0 + wc * 64 + n * 16 + (lane & 15);
        const float bb = ball[gcol];
#pragma unroll
        for (int m = 0; m < 4; m++) {
#pragma unroll
            for (int r = 0; r < 4; r++) {
                const float val = acc[m][n][r] + bb;
                const int row = rb + m * 16 + r;
                if (gcol < 256) {
                    vbf[(size_t)row * 256 + gcol] = f2bf(val);
                } else {
                    const int oc = gcol - 256;
                    if (oc < 432)
                        ombf[(size_t)row * 432 + oc] = f2bf(val);
                }
            }
        }
    }
}

// ---------------------------------------------------------------------------
// Deformable sampling, LDS-tiled + channel-split, gload16 staging.
// 64.5KB LDS -> 2 blocks/CU, 512 blocks exact.
// ---------------------------------------------------------------------------
__global__ __launch_bounds__(512) void dcn_sample(
    const unsigned short* __restrict__ vbf,    // [n][4096][256] bf16
    const unsigned short* __restrict__ ombf,   // [m][432] bf16
    unsigned short* __restrict__ sampled)      // [m][256] bf16
{
    __shared__ unsigned short v_s[144 * 128];  // 36864 B
    __shared__ unsigned short om_s[64 * 216];  // 27648 B
    const int t = threadIdx.x;
    const int b = blockIdx.x;
    const int chalf = b & 1;
    const int tile  = b >> 1;
    const int n   = tile >> 6;
    const int py0 = ((tile >> 3) & 7) * 8;
    const int px0 = (tile & 7) * 8;
    const int y0t = py0 - 2, x0t = px0 - 2;
    const int wub = t & ~63;                   // wave-uniform thread base

    {   // stage v half-tile: 144 slots x 128ch = 2304 uint4 (16B each)
        const unsigned short* vn = vbf + ((size_t)n << 12) * 256 + chalf * 128;
#pragma unroll
        for (int jj = 0; jj < 5; jj++) {
            const int j = jj * 512 + t;
            if (j < 2304) {
                const int slot = j >> 4, wi = j & 15;
                const int ly = slot / 12, lx = slot - ly * 12;
                const int gy = min(max(y0t + ly, 0), 63);
                const int gx = min(max(x0t + lx, 0), 63);
                gload16(vn + (size_t)((gy << 6) + gx) * 256 + wi * 8,
                        v_s + (size_t)(jj * 512 + wub) * 8);
            }
        }
        // stage om half: 64 px x 216 bf16 = 1728 uint4
#pragma unroll
        for (int jj = 0; jj < 4; jj++) {
            const int j = jj * 512 + t;
            if (j < 1728) {
                const int pl = j / 27, wi = j - pl * 27;
                const int m = (n << 12) + ((py0 + (pl >> 3)) << 6) + px0 + (pl & 7);
                gload16(ombf + (size_t)m * OMC + chalf * 216 + wi * 8,
                        om_s + (size_t)(jj * 512 + wub) * 8);
            }
        }
    }
    __syncthreads();

    const int lane  = t & 63;
    const int wv    = t >> 6;            // wave id 0..7
    const int pxsel = lane >> 5;         // 0..1
    const int g     = (lane >> 2) & 7;   // local group 0..7
    const int cl    = lane & 3;
    const int chl   = g * 16 + cl * 4;   // local channel 0..127

#pragma unroll 1
    for (int i = 0; i < 4; i++) {
        const int pl = wv * 8 + i * 2 + pxsel;
        const int h  = py0 + (pl >> 3);
        const int w  = px0 + (pl & 7);
        const unsigned short* omr = om_s + pl * 216 + g * 27;
        float4 acc = make_float4(0.f, 0.f, 0.f, 0.f);
#pragma unroll
        for (int k = 0; k < 9; k++) {
            const float offy = bf2f(omr[2 * k]);
            const float offx = bf2f(omr[2 * k + 1]);
            const float mk   = bf2f(omr[18 + k]);
            const float sy = (float)(h + k / 3 - 1) + offy;
            const float sx = (float)(w + k % 3 - 1) + offx;
            const float y0f = floorf(sy), x0f = floorf(sx);
            const float fy = sy - y0f, fx = sx - x0f;
            const int y0 = (int)y0f, x0 = (int)x0f;
            const float ay  = ((unsigned)y0 < 64u) ? (1.f - fy) : 0.f;
            const float by  = ((unsigned)(y0 + 1) < 64u) ? fy : 0.f;
            const float axm = (((unsigned)x0 < 64u) ? (1.f - fx) : 0.f) * mk;
            const float bxm = (((unsigned)(x0 + 1) < 64u) ? fx : 0.f) * mk;
            const float w00 = ay * axm, w01 = ay * bxm;
            const float w10 = by * axm, w11 = by * bxm;
            const int ly = y0 - y0t, lx = x0 - x0t;
            if ((unsigned)ly <= 10u && (unsigned)lx <= 10u) {
                const unsigned short* p00 = v_s + ((ly * 12 + lx) * 128 + chl);
                acc4(p00,                  w00, acc);
                acc4(p00 + 128,            w01, acc);
                acc4(p00 + 12 * 128,       w10, acc);
                acc4(p00 + 12 * 128 + 128, w11, acc);
            } else {
                const int yc0 = min(max(y0, 0), 63), yc1 = min(max(y0 + 1, 0), 63);
                const int xc0 = min(max(x0, 0), 63), xc1 = min(max(x0 + 1, 0), 63);
                const unsigned short* vg =
                    vbf + ((size_t)n << 12) * 256 + chalf * 128 + chl;
                acc4(vg + (size_t)((yc0 << 6) + xc0) * 256, w00, acc);
                acc4(vg + (size_t)((yc0 << 6) + xc1) * 256, w01, acc);
                acc4(vg + (size_t)((yc1 << 6) + xc0) * 256, w10, acc);
                acc4(vg + (size_t)((yc1 << 6) + xc1) * 256, w11, acc);
            }
        }
        const int m = (n << 12) + (h << 6) + w;
        const unsigned lo = (unsigned)f2bf(acc.x) | ((unsigned)f2bf(acc.y) << 16);
        const unsigned hi = (unsigned)f2bf(acc.z) | ((unsigned)f2bf(acc.w) << 16);
        *reinterpret_cast<uint2*>(sampled + (size_t)m * 256 + chalf * 128 + chl)
            = make_uint2(lo, hi);
    }
}

// ---------------------------------------------------------------------------
// Output GEMM + fused per-block channel stats. o stored bf16; stats from fp32.
// 128x128 tile, BK=32, 4 waves (2x2). 256 blocks = 1/CU exact. XCD-swizzled.
// ---------------------------------------------------------------------------
__global__ __launch_bounds__(256) void gemm_out(
    const unsigned short* __restrict__ A,
    const unsigned short* __restrict__ Bt,
    const float* __restrict__ bias,
    unsigned short* __restrict__ obf,
    float* __restrict__ psum, float* __restrict__ psumsq)
{
    __shared__ unsigned short As[128 * 32];
    __shared__ unsigned short Bs[128 * 32];
    __shared__ float ssum[2][128];
    __shared__ float sqsum[2][128];
    const int t    = threadIdx.x;
    const int lane = t & 63;
    const int wr   = (t >> 7);
    const int wc   = (t >> 6) & 1;
    const int vid = blockIdx.x + 2 * blockIdx.y;
    const int xcd = vid & 7;
    const int j8  = vid >> 3;             // 0..31
    const int by   = xcd * 16 + (j8 >> 1);
    const int row0 = by * 128;
    const int col0 = (j8 & 1) * 128;

    f32x4 acc[4][4];
#pragma unroll
    for (int m = 0; m < 4; m++)
#pragma unroll
        for (int n = 0; n < 4; n++) acc[m][n] = (f32x4)0.f;

    const int r0   = t >> 2;
    const int koff = (t & 3) * 8;
    const unsigned short* gA = A  + (size_t)(row0 + r0) * 256 + koff;
    const unsigned short* gB = Bt + (size_t)(col0 + r0) * 256 + koff;
    const int wbase = (t & 192) * 8;

    const int aoff = ((wr * 64) + (lane & 15)) * 32 + (lane >> 4) * 8;
    const int boff = ((wc * 64) + (lane & 15)) * 32 + (lane >> 4) * 8;

    for (int k0 = 0; k0 < 256; k0 += 32) {
        gload16(gA + k0,            As + wbase);
        gload16(gA + k0 + 64 * 256, As + 2048 + wbase);
        gload16(gB + k0,            Bs + wbase);
        gload16(gB + k0 + 64 * 256, Bs + 2048 + wbase);
        __syncthreads();

        short8v a_[4], b_[4];
#pragma unroll
        for (int m = 0; m < 4; m++)
            a_[m] = *(const short8v*)(As + aoff + m * 16 * 32);
#pragma unroll
        for (int n = 0; n < 4; n++)
            b_[n] = *(const short8v*)(Bs + boff + n * 16 * 32);
#pragma unroll
        for (int m = 0; m < 4; m++)
#pragma unroll
            for (int n = 0; n < 4; n++)
                acc[m][n] = __builtin_amdgcn_mfma_f32_16x16x32_bf16(
                    a_[m], b_[n], acc[m][n], 0, 0, 0);
        __syncthreads();
    }

    const int rbase = row0 + wr * 64 + ((lane >> 4) << 2);
    const int cloc  = wc * 64 + (lane & 15);
#pragma unroll
    for (int n = 0; n < 4; n++) {
        const int col = col0 + cloc + n * 16;
        const float bb = bias[col];
        float s = 0.f, q = 0.f;
#pragma unroll
        for (int m = 0; m < 4; m++) {
#pragma unroll
            for (int r = 0; r < 4; r++) {
                const float val = acc[m][n][r] + bb;
                obf[(size_t)(rbase + m * 16 + r) * C2c + col] = f2bf(val);
                s += val; q += val * val;
            }
        }
        s += __shfl_xor(s, 16); s += __shfl_xor(s, 32);
        q += __shfl_xor(q, 16); q += __shfl_xor(q, 32);
        if (lane < 16) {
            ssum[wr][cloc + n * 16]  = s;
            sqsum[wr][cloc + n * 16] = q;
        }
    }
    __syncthreads();
    if (t < 128) {
        psum[(size_t)by * 256 + col0 + t]   = ssum[0][t] + ssum[1][t];
        psumsq[(size_t)by * 256 + col0 + t] = sqsum[0][t] + sqsum[1][t];
    }
}

// ---------------------------------------------------------------------------
// Fused stats finalize + normalize + SiLU + NHWC->NCHW transpose.
// Grid (16,4,4): block covers 256 px x 64 ch (4 sub-tiles of 64px).
// ---------------------------------------------------------------------------
__global__ __launch_bounds__(256) void norm_silu_transpose(
    const unsigned short* __restrict__ obf,
    const float* __restrict__ psum, const float* __restrict__ psumsq,
    const float* __restrict__ gamma, const float* __restrict__ beta,
    float* __restrict__ out)
{
    __shared__ float tile[64][65];
    __shared__ float sp[4][64], sq[4][64], meanv[64], rsigv[64];
    const int t  = threadIdx.x;
    const int c0 = blockIdx.y * 64;
    const int n  = blockIdx.z;
    const int pb = blockIdx.x * 256;

    // ---- stats prelude: 128-row reduce for this block's 64 channels ----
    {
        const int lc = t & 63, rq = t >> 6;
        float s = 0.f, q = 0.f;
        const float* ps = psum   + (size_t)(rq * 32) * 256 + c0 + lc;
        const float* pq = psumsq + (size_t)(rq * 32) * 256 + c0 + lc;
#pragma unroll 4
        for (int r = 0; r < 32; r++) {
            s += ps[(size_t)r * 256];
            q += pq[(size_t)r * 256];
        }
        sp[rq][lc] = s; sq[rq][lc] = q;
    }
    __syncthreads();
    if (t < 64) {
        const float ss = (sp[0][t] + sp[1][t]) + (sp[2][t] + sp[3][t]);
        const float qq = (sq[0][t] + sq[1][t]) + (sq[2][t] + sq[3][t]);
        const float inv = 1.f / (float)Mrows;
        const float mean = ss * inv;
        const float var  = qq * inv - mean * mean;
        meanv[t] = mean;
        rsigv[t] = rsqrtf(var + EPSc);
    }
    __syncthreads();

    const int lp = t & 63, lcq = t >> 6;
    float gv[16], bvv[16];
#pragma unroll
    for (int i = 0; i < 16; i++) {
        gv[i]  = gamma[c0 + lcq * 16 + i];
        bvv[i] = beta[c0 + lcq * 16 + i];
    }

#pragma unroll 1
    for (int st = 0; st < 4; st++) {
        const int p0 = pb + st * 64;
        const int m0 = n * HWc + p0;
#pragma unroll
        for (int i = 0; i < 8; i++) {
            const int idx = i * 256 + t;
            const int p  = idx >> 5;
            const int cp = (idx & 31) * 2;
            const unsigned u = *reinterpret_cast<const unsigned*>(
                obf + (size_t)(m0 + p) * C2c + c0 + cp);
            tile[p][cp]     = __builtin_bit_cast(float, u << 16);
            tile[p][cp + 1] = __builtin_bit_cast(float, u & 0xffff0000u);
        }
        __syncthreads();
#pragma unroll
        for (int i = 0; i < 16; i++) {
            const int c  = lcq * 16 + i;
            const int ch = c0 + c;
            const float x = tile[lp][c];
            const float y = gv[i] * (x - meanv[c]) * rsigv[c] + bvv[i];
            const float sy = y / (1.f + expf(-y));
            out[(size_t)n * C2c * HWc + (size_t)ch * HWc + p0 + lp] = sy;
        }
        __syncthreads();
    }
}

// ---------------------------------------------------------------------------
extern "C" void kernel_launch(void* const* d_in, const int* in_sizes, int n_in,
                              void* d_out, int out_size, void* d_ws, size_t ws_size,
                              hipStream_t stream)
{
    const float* x     = (const float*)d_in[0];
    const float* Wv    = (const float*)d_in[1];
    const float* bv    = (const float*)d_in[2];
    const float* Wom   = (const float*)d_in[3];
    const float* bom   = (const float*)d_in[4];
    const float* Wout  = (const float*)d_in[5];
    const float* bout  = (const float*)d_in[6];
    const float* gamma = (const float*)d_in[7];
    const float* beta  = (const float*)d_in[8];
    float* out = (float*)d_out;

    unsigned short* us = (unsigned short*)d_ws;
    unsigned short* Ax    = us;                    // 4,194,304
    unsigned short* vbf   = Ax + 4194304;          // 4,194,304
    unsigned short* ombf  = vbf + 4194304;         // 7,077,888
    unsigned short* samp  = ombf + 7077888;        // 4,194,304
    unsigned short* obf   = samp + 4194304;        // 4,194,304
    unsigned short* WallT = obf + 4194304;         // 196,608
    unsigned short* WoutT = WallT + 196608;        // 65,536
    float* fs     = (float*)(WoutT + 65536);
    float* psum   = fs;                            // 32,768
    float* psumsq = psum + 32768;                  // 32,768
    float* ball   = psumsq + 32768;                // 768

    // fused conversions (x transpose + weights)
    prep<<<2051, 256, 0, stream>>>(x, Wv, Wom, Wout, bv, bom,
                                   Ax, WallT, WoutT, ball);
    // v (cols 0..255) + om (cols 256..687), 128x128 tiles, 3 blocks/CU exact
    gemm_vom<<<dim3(6, 128), 256, 0, stream>>>(Ax, WallT, ball, vbf, ombf);
    // deformable sampling (LDS-tiled, channel-split, gload16 staging)
    dcn_sample<<<512, 512, 0, stream>>>(vbf, ombf, samp);
    // o = sampled @ Wout + bout -> bf16, with fused per-block channel stats
    gemm_out<<<dim3(2, 128), 256, 0, stream>>>(samp, WoutT, bout, obf, psum, psumsq);
    // fused stats finalize + normalize + SiLU + transpose
    norm_silu_transpose<<<dim3(16, 4, 4), 256, 0, stream>>>(obf, psum, psumsq,
                                                            gamma, beta, out);
}